// Round 1
// baseline (474.068 us; speedup 1.0000x reference)
//
#include <hip/hip_runtime.h>

typedef __attribute__((ext_vector_type(8))) short   short8;
typedef __attribute__((ext_vector_type(8))) __bf16  bf16x8;
typedef __attribute__((ext_vector_type(4))) float   f32x4;

#define NSTEPS 49

static __device__ __forceinline__ short8 as_s8(bf16x8 v) {
    return __builtin_bit_cast(short8, v);
}

#define MFMA(A, B, C) __builtin_amdgcn_mfma_f32_16x16x32_bf16((A), (B), (C), 0, 0, 0)

// Build the two B-frag slices covering 64 state dims from f32x4 SRC[4].
// Slice ks, lane(q,c), slot j holds dim 32ks+16(j>>2)+4q+(j&3)  == SRC[2ks+(j>>2)][j&3].
#define BUILD_XS(SRC)                                                     \
    {                                                                     \
        bf16x8 v0_, v1_;                                                  \
        v0_[0] = (__bf16)(SRC)[0][0]; v0_[1] = (__bf16)(SRC)[0][1];       \
        v0_[2] = (__bf16)(SRC)[0][2]; v0_[3] = (__bf16)(SRC)[0][3];       \
        v0_[4] = (__bf16)(SRC)[1][0]; v0_[5] = (__bf16)(SRC)[1][1];       \
        v0_[6] = (__bf16)(SRC)[1][2]; v0_[7] = (__bf16)(SRC)[1][3];       \
        v1_[0] = (__bf16)(SRC)[2][0]; v1_[1] = (__bf16)(SRC)[2][1];       \
        v1_[2] = (__bf16)(SRC)[2][2]; v1_[3] = (__bf16)(SRC)[2][3];       \
        v1_[4] = (__bf16)(SRC)[3][0]; v1_[5] = (__bf16)(SRC)[3][1];       \
        v1_[6] = (__bf16)(SRC)[3][2]; v1_[7] = (__bf16)(SRC)[3][3];       \
        xs0 = as_s8(v0_); xs1 = as_s8(v1_);                               \
    }

// Third L1 K-slice: k=64 carries t, k=65 carries constant 1.0 (bias column).
#define BUILD_XT(TV)                                                      \
    {                                                                     \
        bf16x8 v_;                                                        \
        _Pragma("unroll") for (int j_ = 0; j_ < 8; ++j_) v_[j_] = (__bf16)0.f; \
        if (q == 0) { v_[0] = (__bf16)(TV); v_[1] = (__bf16)1.0f; }       \
        xt = as_s8(v_);                                                   \
    }

// Full 3-layer MLP, entirely in registers. Output KK[t][r] = k[c][16t+4q+r].
#define MLP_EVAL(KK)                                                      \
    {                                                                     \
        const f32x4 zz_ = {0.f, 0.f, 0.f, 0.f};                           \
        f32x4 a1_[8];                                                     \
        _Pragma("unroll")                                                 \
        for (int t_ = 0; t_ < 8; ++t_) {                                  \
            f32x4 ac_ = MFMA(wA0[t_][0], xs0, zz_);                       \
            ac_ = MFMA(wA0[t_][1], xs1, ac_);                             \
            ac_ = MFMA(wA0[t_][2], xt,  ac_);                             \
            a1_[t_] = ac_;                                                \
        }                                                                 \
        short8 xh_[4];                                                    \
        _Pragma("unroll")                                                 \
        for (int ks_ = 0; ks_ < 4; ++ks_) {                               \
            bf16x8 v_;                                                    \
            v_[0] = (__bf16)fmaxf(a1_[2*ks_  ][0], 0.f);                  \
            v_[1] = (__bf16)fmaxf(a1_[2*ks_  ][1], 0.f);                  \
            v_[2] = (__bf16)fmaxf(a1_[2*ks_  ][2], 0.f);                  \
            v_[3] = (__bf16)fmaxf(a1_[2*ks_  ][3], 0.f);                  \
            v_[4] = (__bf16)fmaxf(a1_[2*ks_+1][0], 0.f);                  \
            v_[5] = (__bf16)fmaxf(a1_[2*ks_+1][1], 0.f);                  \
            v_[6] = (__bf16)fmaxf(a1_[2*ks_+1][2], 0.f);                  \
            v_[7] = (__bf16)fmaxf(a1_[2*ks_+1][3], 0.f);                  \
            xh_[ks_] = as_s8(v_);                                         \
        }                                                                 \
        f32x4 a2_[8];                                                     \
        _Pragma("unroll")                                                 \
        for (int t_ = 0; t_ < 8; ++t_) {                                  \
            f32x4 ac_ = MFMA(wA1[t_][0], xh_[0], zz_);                    \
            ac_ = MFMA(wA1[t_][1], xh_[1], ac_);                          \
            ac_ = MFMA(wA1[t_][2], xh_[2], ac_);                          \
            ac_ = MFMA(wA1[t_][3], xh_[3], ac_);                          \
            a2_[t_] = ac_;                                                \
        }                                                                 \
        short8 xg_[4];                                                    \
        _Pragma("unroll")                                                 \
        for (int ks_ = 0; ks_ < 4; ++ks_) {                               \
            bf16x8 v_;                                                    \
            v_[0] = (__bf16)fmaxf(a2_[2*ks_  ][0] + bL2[2*ks_  ], 0.f);   \
            v_[1] = (__bf16)fmaxf(a2_[2*ks_  ][1] + bL2[2*ks_  ], 0.f);   \
            v_[2] = (__bf16)fmaxf(a2_[2*ks_  ][2] + bL2[2*ks_  ], 0.f);   \
            v_[3] = (__bf16)fmaxf(a2_[2*ks_  ][3] + bL2[2*ks_  ], 0.f);   \
            v_[4] = (__bf16)fmaxf(a2_[2*ks_+1][0] + bL2[2*ks_+1], 0.f);   \
            v_[5] = (__bf16)fmaxf(a2_[2*ks_+1][1] + bL2[2*ks_+1], 0.f);   \
            v_[6] = (__bf16)fmaxf(a2_[2*ks_+1][2] + bL2[2*ks_+1], 0.f);   \
            v_[7] = (__bf16)fmaxf(a2_[2*ks_+1][3] + bL2[2*ks_+1], 0.f);   \
            xg_[ks_] = as_s8(v_);                                         \
        }                                                                 \
        _Pragma("unroll")                                                 \
        for (int t_ = 0; t_ < 4; ++t_) {                                  \
            f32x4 ac_ = MFMA(wA2[t_][0], xg_[0], zz_);                    \
            ac_ = MFMA(wA2[t_][1], xg_[1], ac_);                          \
            ac_ = MFMA(wA2[t_][2], xg_[2], ac_);                          \
            ac_ = MFMA(wA2[t_][3], xg_[3], ac_);                          \
            KK[t_] = ac_ + bL3[t_];                                       \
        }                                                                 \
    }

// One wave per block owns 16 batch rows and the entire MLP.
// Weights live in registers/AGPRs (K-permuted so each layer's MFMA C-layout
// IS the next layer's B-frag layout). Zero LDS, zero barriers, zero shuffles.
extern "C" __global__ void __launch_bounds__(64, 1)
node_solve(const float* __restrict__ y0, const float* __restrict__ ts,
           const float* __restrict__ gw0, const float* __restrict__ gb0,
           const float* __restrict__ gw1, const float* __restrict__ gb1,
           const float* __restrict__ gw2, const float* __restrict__ gb2,
           float* __restrict__ out)
{
    const int lane = threadIdx.x & 63;
    const int q    = lane >> 4;
    const int c    = lane & 15;
    const int row0 = blockIdx.x << 4;

    // ---- weights -> K-permuted register A-frags ----
    // perm: k-position 32ks+8q+j  <-  source column 32ks+16*(j>>2)+4q+(j&3)
    short8 wA0[8][3];   // L1: 128 neurons x K=96 (y dims + [t, bias-1] slice)
    short8 wA1[8][4];   // L2: 128 x 128
    short8 wA2[4][4];   // L3: 64 x 128
    float  bL2[8], bL3[4];

    #pragma unroll
    for (int t = 0; t < 8; ++t) {
        const int n = 16 * t + c;
        const float* w0r = gw0 + n * 65 + 1;      // col 0 of gw0 is the t-weight
        #pragma unroll
        for (int ks = 0; ks < 2; ++ks) {
            bf16x8 v;
            #pragma unroll
            for (int j = 0; j < 8; ++j)
                v[j] = (__bf16)w0r[32*ks + 16*(j>>2) + 4*q + (j&3)];
            wA0[t][ks] = as_s8(v);
        }
        {
            bf16x8 v;
            #pragma unroll
            for (int j = 0; j < 8; ++j) v[j] = (__bf16)0.f;
            if (q == 0) { v[0] = (__bf16)gw0[n*65]; v[1] = (__bf16)gb0[n]; }
            wA0[t][2] = as_s8(v);
        }
        const float* w1r = gw1 + n * 128;
        #pragma unroll
        for (int ks = 0; ks < 4; ++ks) {
            bf16x8 v;
            #pragma unroll
            for (int j = 0; j < 8; ++j)
                v[j] = (__bf16)w1r[32*ks + 16*(j>>2) + 4*q + (j&3)];
            wA1[t][ks] = as_s8(v);
        }
        bL2[t] = gb1[16*t + c];
    }
    #pragma unroll
    for (int t = 0; t < 4; ++t) {
        const int n = 16 * t + c;
        const float* w2r = gw2 + n * 128;
        #pragma unroll
        for (int ks = 0; ks < 4; ++ks) {
            bf16x8 v;
            #pragma unroll
            for (int j = 0; j < 8; ++j)
                v[j] = (__bf16)w2r[32*ks + 16*(j>>2) + 4*q + (j&3)];
            wA2[t][ks] = as_s8(v);
        }
        bL3[t] = gb2[16*t + c];
    }

    // ---- persistent state: y[t][r] = y[row0+c][16t+4q+r] ----
    f32x4 y[4];
    #pragma unroll
    for (int t = 0; t < 4; ++t)
        y[t] = *(const f32x4*)(y0 + (size_t)(row0 + c) * 64 + 16*t + 4*q);

    const float ts0 = ts[0];
    const float dtv = ts[1] - ts[0];

    // dt-scaled Tsit5 tableau (hoisted scalars)
    const float d21 = dtv * 0.161f;
    const float d31 = dtv * -0.008480655492356989f, d32 = dtv * 0.335480655492357f;
    const float d41 = dtv * 2.8971530571054935f,  d42 = dtv * -6.359448489975075f,  d43 = dtv * 4.3622954328695815f;
    const float d51 = dtv * 5.325864828439257f,   d52 = dtv * -11.748883564062828f, d53 = dtv * 7.4955393428898365f, d54 = dtv * -0.09249506636175525f;
    const float d61 = dtv * 5.86145544294642f,    d62 = dtv * -12.92096931784711f,  d63 = dtv * 8.159367898576159f,  d64 = dtv * -0.071584973281401f, d65 = dtv * -0.028269050394068383f;
    const float e1  = dtv * 0.09646076681806523f, e2  = dtv * 0.01f,                e3  = dtv * 0.4798896504144996f;
    const float e4  = dtv * 1.379008574103742f,   e5  = dtv * -3.290069515436081f,  e6  = dtv * 2.324710524099774f;

    short8 xs0, xs1, xt;

    #pragma unroll 1
    for (int step = 0; step < NSTEPS; ++step) {
        const float t0s = ts0 + (float)step * dtv;
        f32x4 k0v[4], k1v[4], k2v[4], k3v[4], k4v[4], k5v[4];
        f32x4 si[4];

        // stage 1
        BUILD_XS(y); BUILD_XT(t0s);
        MLP_EVAL(k0v);

        // stage 2
        #pragma unroll
        for (int t = 0; t < 4; ++t) si[t] = y[t] + d21 * k0v[t];
        BUILD_XS(si); BUILD_XT(t0s + 0.161f * dtv);
        MLP_EVAL(k1v);

        // stage 3
        #pragma unroll
        for (int t = 0; t < 4; ++t) si[t] = y[t] + d31*k0v[t] + d32*k1v[t];
        BUILD_XS(si); BUILD_XT(t0s + 0.327f * dtv);
        MLP_EVAL(k2v);

        // stage 4
        #pragma unroll
        for (int t = 0; t < 4; ++t) si[t] = y[t] + d41*k0v[t] + d42*k1v[t] + d43*k2v[t];
        BUILD_XS(si); BUILD_XT(t0s + 0.9f * dtv);
        MLP_EVAL(k3v);

        // stage 5
        #pragma unroll
        for (int t = 0; t < 4; ++t) si[t] = y[t] + d51*k0v[t] + d52*k1v[t] + d53*k2v[t] + d54*k3v[t];
        BUILD_XS(si); BUILD_XT(t0s + 0.9800255409045097f * dtv);
        MLP_EVAL(k4v);

        // stage 6
        #pragma unroll
        for (int t = 0; t < 4; ++t) si[t] = y[t] + d61*k0v[t] + d62*k1v[t] + d63*k2v[t] + d64*k3v[t] + d65*k4v[t];
        BUILD_XS(si); BUILD_XT(t0s + dtv);
        MLP_EVAL(k5v);

        // 5th-order update
        #pragma unroll
        for (int t = 0; t < 4; ++t)
            y[t] = y[t] + e1*k0v[t] + e2*k1v[t] + e3*k2v[t] + e4*k3v[t] + e5*k4v[t] + e6*k5v[t];
    }

    #pragma unroll
    for (int t = 0; t < 4; ++t)
        *(f32x4*)(out + (size_t)(row0 + c) * 64 + 16*t + 4*q) = y[t];
}

extern "C" void kernel_launch(void* const* d_in, const int* in_sizes, int n_in,
                              void* d_out, int out_size, void* d_ws, size_t ws_size,
                              hipStream_t stream) {
    const float* y0 = (const float*)d_in[0];
    const float* ts = (const float*)d_in[1];
    const float* w0 = (const float*)d_in[2];
    const float* b0 = (const float*)d_in[3];
    const float* w1 = (const float*)d_in[4];
    const float* b1 = (const float*)d_in[5];
    const float* w2 = (const float*)d_in[6];
    const float* b2 = (const float*)d_in[7];
    float* out = (float*)d_out;

    node_solve<<<dim3(128), dim3(64), 0, stream>>>(y0, ts, w0, b0, w1, b1, w2, b2, out);
}

// Round 2
// 397.855 us; speedup vs baseline: 1.1916x; 1.1916x over previous
//
#include <hip/hip_runtime.h>

typedef __attribute__((ext_vector_type(8))) short   short8;
typedef __attribute__((ext_vector_type(8))) __bf16  bf16x8;
typedef __attribute__((ext_vector_type(4))) float   f32x4;

#define NSTEPS 49

static __device__ __forceinline__ short8 as_s8(bf16x8 v) {
    return __builtin_bit_cast(short8, v);
}

#define MFMA(A, B, C) __builtin_amdgcn_mfma_f32_16x16x32_bf16((A), (B), (C), 0, 0, 0)

// xs slices from f32x4 SRC[4]: slice0[j] = SRC[j>>2][j&3], slice1[j] = SRC[(j>>2)+2][j&3]
#define BUILD_XS(SRC)                                                        \
    {                                                                        \
        bf16x8 v0_, v1_;                                                     \
        _Pragma("unroll")                                                    \
        for (int j_ = 0; j_ < 8; ++j_) {                                     \
            v0_[j_] = (__bf16)(SRC)[j_ >> 2][j_ & 3];                        \
            v1_[j_] = (__bf16)(SRC)[(j_ >> 2) + 2][j_ & 3];                  \
        }                                                                    \
        xs0 = as_s8(v0_); xs1 = as_s8(v1_);                                  \
    }

// Third L1 K-slice: k=64 carries t, k=65 carries constant 1.0 (bias column).
#define BUILD_XT(TV)                                                         \
    {                                                                        \
        bf16x8 v_;                                                           \
        _Pragma("unroll") for (int j_ = 0; j_ < 8; ++j_) v_[j_] = (__bf16)0.f; \
        if (q == 0) { v_[0] = (__bf16)(TV); v_[1] = (__bf16)1.0f; }          \
        xt = as_s8(v_);                                                      \
    }

// Store fresh f32 k (f32x4[4]) as packed bf16 in xs-slice order (8 VGPRs).
#define STORE_KB(KB, KV)                                                     \
    {                                                                        \
        bf16x8 t0_, t1_;                                                     \
        _Pragma("unroll")                                                    \
        for (int j_ = 0; j_ < 8; ++j_) {                                     \
            t0_[j_] = (__bf16)(KV)[j_ >> 2][j_ & 3];                         \
            t1_[j_] = (__bf16)(KV)[(j_ >> 2) + 2][j_ & 3];                   \
        }                                                                    \
        (KB)[0] = t0_; (KB)[1] = t1_;                                        \
    }

// Unpack one bf16 k value (V = 0..15, compile-time in unrolled loops).
#define KF(KB, V) ((float)(KB)[(V) >> 3][(V) & 7])

// Full 3-layer MLP in registers; per-pair tile processing keeps live
// accumulators to 2 f32x4. Output KV[t][r] = k[c][16t+4q+r] (f32, +bias).
#define MLP_EVAL(KV)                                                         \
    {                                                                        \
        const f32x4 zz_ = {0.f, 0.f, 0.f, 0.f};                              \
        short8 xh_[4];                                                       \
        _Pragma("unroll")                                                    \
        for (int ks_ = 0; ks_ < 4; ++ks_) {                                  \
            f32x4 aA_ = MFMA(wA0[2*ks_  ][0], xs0, zz_);                     \
            aA_ = MFMA(wA0[2*ks_  ][1], xs1, aA_);                           \
            aA_ = MFMA(wA0[2*ks_  ][2], xt,  aA_);                           \
            f32x4 aB_ = MFMA(wA0[2*ks_+1][0], xs0, zz_);                     \
            aB_ = MFMA(wA0[2*ks_+1][1], xs1, aB_);                           \
            aB_ = MFMA(wA0[2*ks_+1][2], xt,  aB_);                           \
            bf16x8 v_;                                                       \
            v_[0] = (__bf16)fmaxf(aA_[0], 0.f);                              \
            v_[1] = (__bf16)fmaxf(aA_[1], 0.f);                              \
            v_[2] = (__bf16)fmaxf(aA_[2], 0.f);                              \
            v_[3] = (__bf16)fmaxf(aA_[3], 0.f);                              \
            v_[4] = (__bf16)fmaxf(aB_[0], 0.f);                              \
            v_[5] = (__bf16)fmaxf(aB_[1], 0.f);                              \
            v_[6] = (__bf16)fmaxf(aB_[2], 0.f);                              \
            v_[7] = (__bf16)fmaxf(aB_[3], 0.f);                              \
            xh_[ks_] = as_s8(v_);                                            \
        }                                                                    \
        short8 xg_[4];                                                       \
        _Pragma("unroll")                                                    \
        for (int ks_ = 0; ks_ < 4; ++ks_) {                                  \
            f32x4 aA_ = MFMA(wA1[2*ks_  ][0], xh_[0], zz_);                  \
            aA_ = MFMA(wA1[2*ks_  ][1], xh_[1], aA_);                        \
            aA_ = MFMA(wA1[2*ks_  ][2], xh_[2], aA_);                        \
            aA_ = MFMA(wA1[2*ks_  ][3], xh_[3], aA_);                        \
            f32x4 aB_ = MFMA(wA1[2*ks_+1][0], xh_[0], zz_);                  \
            aB_ = MFMA(wA1[2*ks_+1][1], xh_[1], aB_);                        \
            aB_ = MFMA(wA1[2*ks_+1][2], xh_[2], aB_);                        \
            aB_ = MFMA(wA1[2*ks_+1][3], xh_[3], aB_);                        \
            bf16x8 v_;                                                       \
            v_[0] = (__bf16)fmaxf(aA_[0] + bL2[2*ks_  ], 0.f);               \
            v_[1] = (__bf16)fmaxf(aA_[1] + bL2[2*ks_  ], 0.f);               \
            v_[2] = (__bf16)fmaxf(aA_[2] + bL2[2*ks_  ], 0.f);               \
            v_[3] = (__bf16)fmaxf(aA_[3] + bL2[2*ks_  ], 0.f);               \
            v_[4] = (__bf16)fmaxf(aB_[0] + bL2[2*ks_+1], 0.f);               \
            v_[5] = (__bf16)fmaxf(aB_[1] + bL2[2*ks_+1], 0.f);               \
            v_[6] = (__bf16)fmaxf(aB_[2] + bL2[2*ks_+1], 0.f);               \
            v_[7] = (__bf16)fmaxf(aB_[3] + bL2[2*ks_+1], 0.f);               \
            xg_[ks_] = as_s8(v_);                                            \
        }                                                                    \
        _Pragma("unroll")                                                    \
        for (int t_ = 0; t_ < 4; ++t_) {                                     \
            f32x4 ac_ = MFMA(wA2[t_][0], xg_[0], zz_);                       \
            ac_ = MFMA(wA2[t_][1], xg_[1], ac_);                             \
            ac_ = MFMA(wA2[t_][2], xg_[2], ac_);                             \
            ac_ = MFMA(wA2[t_][3], xg_[3], ac_);                             \
            KV[t_] = ac_ + bL3[t_];                                          \
        }                                                                    \
    }

// One wave per block owns 16 batch rows and the entire MLP.
// Weights (288 regs) live in the AGPR side of the unified file (MFMA-only
// consumers); VALU-live state is kept under 256 architected VGPRs by
// storing k0..k4 as packed bf16 (stage inputs are rounded to bf16 for the
// MFMA anyway) while the 5th-order y-update accumulates fresh f32 k's.
// Zero LDS, zero barriers, zero shuffles.
extern "C" __global__ void __launch_bounds__(64, 1)
node_solve(const float* __restrict__ y0, const float* __restrict__ ts,
           const float* __restrict__ gw0, const float* __restrict__ gb0,
           const float* __restrict__ gw1, const float* __restrict__ gb1,
           const float* __restrict__ gw2, const float* __restrict__ gb2,
           float* __restrict__ out)
{
    const int lane = threadIdx.x & 63;
    const int q    = lane >> 4;
    const int c    = lane & 15;
    const int row0 = blockIdx.x << 4;

    // ---- weights -> K-permuted register A-frags ----
    // perm: k-position 32ks+8q+j  <-  source column 32ks+16*(j>>2)+4q+(j&3)
    short8 wA0[8][3];   // L1: 128 neurons x K=96 (y dims + [t, bias-1] slice)
    short8 wA1[8][4];   // L2: 128 x 128
    short8 wA2[4][4];   // L3: 64 x 128
    float  bL2[8], bL3[4];

    #pragma unroll
    for (int t = 0; t < 8; ++t) {
        const int n = 16 * t + c;
        const float* w0r = gw0 + n * 65 + 1;      // col 0 of gw0 is the t-weight
        #pragma unroll
        for (int ks = 0; ks < 2; ++ks) {
            bf16x8 v;
            #pragma unroll
            for (int j = 0; j < 8; ++j)
                v[j] = (__bf16)w0r[32*ks + 16*(j>>2) + 4*q + (j&3)];
            wA0[t][ks] = as_s8(v);
        }
        {
            bf16x8 v;
            #pragma unroll
            for (int j = 0; j < 8; ++j) v[j] = (__bf16)0.f;
            if (q == 0) { v[0] = (__bf16)gw0[n*65]; v[1] = (__bf16)gb0[n]; }
            wA0[t][2] = as_s8(v);
        }
        const float* w1r = gw1 + n * 128;
        #pragma unroll
        for (int ks = 0; ks < 4; ++ks) {
            bf16x8 v;
            #pragma unroll
            for (int j = 0; j < 8; ++j)
                v[j] = (__bf16)w1r[32*ks + 16*(j>>2) + 4*q + (j&3)];
            wA1[t][ks] = as_s8(v);
        }
        bL2[t] = gb1[16*t + c];
    }
    #pragma unroll
    for (int t = 0; t < 4; ++t) {
        const int n = 16 * t + c;
        const float* w2r = gw2 + n * 128;
        #pragma unroll
        for (int ks = 0; ks < 4; ++ks) {
            bf16x8 v;
            #pragma unroll
            for (int j = 0; j < 8; ++j)
                v[j] = (__bf16)w2r[32*ks + 16*(j>>2) + 4*q + (j&3)];
            wA2[t][ks] = as_s8(v);
        }
        bL3[t] = gb2[16*t + c];
    }

    // ---- persistent state: y[t][r] = y[row0+c][16t+4q+r] ----
    f32x4 y[4];
    #pragma unroll
    for (int t = 0; t < 4; ++t)
        y[t] = *(const f32x4*)(y0 + (size_t)(row0 + c) * 64 + 16*t + 4*q);

    const float ts0 = ts[0];
    const float dtv = ts[1] - ts[0];

    // dt-scaled Tsit5 tableau (hoisted scalars)
    const float d21 = dtv * 0.161f;
    const float d31 = dtv * -0.008480655492356989f, d32 = dtv * 0.335480655492357f;
    const float d41 = dtv * 2.8971530571054935f,  d42 = dtv * -6.359448489975075f,  d43 = dtv * 4.3622954328695815f;
    const float d51 = dtv * 5.325864828439257f,   d52 = dtv * -11.748883564062828f, d53 = dtv * 7.4955393428898365f, d54 = dtv * -0.09249506636175525f;
    const float d61 = dtv * 5.86145544294642f,    d62 = dtv * -12.92096931784711f,  d63 = dtv * 8.159367898576159f,  d64 = dtv * -0.071584973281401f, d65 = dtv * -0.028269050394068383f;
    const float e1  = dtv * 0.09646076681806523f, e2  = dtv * 0.01f,                e3  = dtv * 0.4798896504144996f;
    const float e4  = dtv * 1.379008574103742f,   e5  = dtv * -3.290069515436081f,  e6  = dtv * 2.324710524099774f;

    short8 xs0, xs1, xt;

    #pragma unroll 1
    for (int step = 0; step < NSTEPS; ++step) {
        const float t0s = ts0 + (float)step * dtv;
        f32x4 kv[4], si[4], yn[4];
        bf16x8 kb0[2], kb1[2], kb2[2], kb3[2], kb4[2];

        // ---- stage 1 ----
        BUILD_XS(y); BUILD_XT(t0s);
        MLP_EVAL(kv);
        #pragma unroll
        for (int t = 0; t < 4; ++t) yn[t] = y[t] + e1 * kv[t];
        STORE_KB(kb0, kv);

        // ---- stage 2 ----
        #pragma unroll
        for (int v = 0; v < 16; ++v)
            si[v>>2][v&3] = y[v>>2][v&3] + d21*KF(kb0,v);
        BUILD_XS(si); BUILD_XT(t0s + 0.161f * dtv);
        MLP_EVAL(kv);
        #pragma unroll
        for (int t = 0; t < 4; ++t) yn[t] += e2 * kv[t];
        STORE_KB(kb1, kv);

        // ---- stage 3 ----
        #pragma unroll
        for (int v = 0; v < 16; ++v)
            si[v>>2][v&3] = y[v>>2][v&3] + d31*KF(kb0,v) + d32*KF(kb1,v);
        BUILD_XS(si); BUILD_XT(t0s + 0.327f * dtv);
        MLP_EVAL(kv);
        #pragma unroll
        for (int t = 0; t < 4; ++t) yn[t] += e3 * kv[t];
        STORE_KB(kb2, kv);

        // ---- stage 4 ----
        #pragma unroll
        for (int v = 0; v < 16; ++v)
            si[v>>2][v&3] = y[v>>2][v&3] + d41*KF(kb0,v) + d42*KF(kb1,v) + d43*KF(kb2,v);
        BUILD_XS(si); BUILD_XT(t0s + 0.9f * dtv);
        MLP_EVAL(kv);
        #pragma unroll
        for (int t = 0; t < 4; ++t) yn[t] += e4 * kv[t];
        STORE_KB(kb3, kv);

        // ---- stage 5 ----
        #pragma unroll
        for (int v = 0; v < 16; ++v)
            si[v>>2][v&3] = y[v>>2][v&3] + d51*KF(kb0,v) + d52*KF(kb1,v) + d53*KF(kb2,v) + d54*KF(kb3,v);
        BUILD_XS(si); BUILD_XT(t0s + 0.9800255409045097f * dtv);
        MLP_EVAL(kv);
        #pragma unroll
        for (int t = 0; t < 4; ++t) yn[t] += e5 * kv[t];
        STORE_KB(kb4, kv);

        // ---- stage 6 ----
        #pragma unroll
        for (int v = 0; v < 16; ++v)
            si[v>>2][v&3] = y[v>>2][v&3] + d61*KF(kb0,v) + d62*KF(kb1,v) + d63*KF(kb2,v) + d64*KF(kb3,v) + d65*KF(kb4,v);
        BUILD_XS(si); BUILD_XT(t0s + dtv);
        MLP_EVAL(kv);
        #pragma unroll
        for (int t = 0; t < 4; ++t) y[t] = yn[t] + e6 * kv[t];
    }

    #pragma unroll
    for (int t = 0; t < 4; ++t)
        *(f32x4*)(out + (size_t)(row0 + c) * 64 + 16*t + 4*q) = y[t];
}

extern "C" void kernel_launch(void* const* d_in, const int* in_sizes, int n_in,
                              void* d_out, int out_size, void* d_ws, size_t ws_size,
                              hipStream_t stream) {
    const float* y0 = (const float*)d_in[0];
    const float* ts = (const float*)d_in[1];
    const float* w0 = (const float*)d_in[2];
    const float* b0 = (const float*)d_in[3];
    const float* w1 = (const float*)d_in[4];
    const float* b1 = (const float*)d_in[5];
    const float* w2 = (const float*)d_in[6];
    const float* b2 = (const float*)d_in[7];
    float* out = (float*)d_out;

    node_solve<<<dim3(128), dim3(64), 0, stream>>>(y0, ts, w0, b0, w1, b1, w2, b2, out);
}